// Round 2
// baseline (990.663 us; speedup 1.0000x reference)
//
#include <hip/hip_runtime.h>
#include <math.h>

#define NC1 150
#define HW 196          // 14*14
#define CSTRIDE 152     // 150 padded to multiple of 4 (pad written as 0)
#define NTOT (HW*CSTRIDE)   // 29792
#define NB 1024
#define DD 32
#define NHD 4
#define HDIM 8
#define KG 2352         // ceil(0.08 * 150*14*14)
#define KCH 10

// ---------------- K0: 2D sinusoidal positional embedding [196,32] ----------------
__global__ void pos2d_kernel(float* __restrict__ pos) {
  int i = blockIdx.x * 256 + threadIdx.x;
  if (i >= HW * DD) return;
  int s = i >> 5, d = i & 31;
  int h = s / 14, w = s % 14;
  int p = (d < 16) ? h : w;
  int dd = (d < 16) ? d : d - 16;
  int j = dd >> 1;
  float dv = expf(-(logf(10000.0f) / 16.0f) * (float)(2 * j));
  float ang = (float)p * dv;
  pos[i] = (dd & 1) ? cosf(ang) : sinf(ang);
}

// ---------------- K1: conv 9x9 stride2 pad4 + relu -> A[b][s][c] (c-stride 152) ----------------
// R2 change: desynchronize the channel-group walk across waves/blocks so the
// per-group s_load -> s_waitcnt lgkmcnt(0) stall of one wave overlaps other
// waves' FMA phases (they are at different groups). 16 distinct start offsets
// (widx*5 % 38) spread the 16 resident waves per CU over the 38 groups.
__global__ __launch_bounds__(256) void conv_kernel(const float* __restrict__ x,
                                                   const float* __restrict__ cw,
                                                   float* __restrict__ A) {
  __shared__ float xs[784];
  int b = blockIdx.x, tid = threadIdx.x;
  if (tid < 196) ((float4*)xs)[tid] = ((const float4*)(x + (size_t)b * 784))[tid];
  __syncthreads();
  if (tid >= 196) return;
  int s = tid, h = s / 14, w = s % 14;
  float xr[81];
#pragma unroll
  for (int i = 0; i < 9; ++i) {
    int r = 2 * h - 4 + i;
    bool rok = (r >= 0 && r < 28);
#pragma unroll
    for (int j = 0; j < 9; ++j) {
      int cl = 2 * w - 4 + j;
      xr[i * 9 + j] = (rok && cl >= 0 && cl < 28) ? xs[r * 28 + cl] : 0.0f;
    }
  }
  float* As = A + (size_t)b * NTOT + s * CSTRIDE;
  int widx = ((b & 3) << 2) | (tid >> 6);       // 0..15, uniform per wave
  int start = (widx * 5) % 38;                  // 0,5,10,...,35,2,7,...,37
  for (int gg = 0; gg < 38; ++gg) {
    int g = start + gg; if (g >= 38) g -= 38;
    float acc0 = 0.f, acc1 = 0.f, acc2 = 0.f, acc3 = 0.f;
    int c0 = g * 4;
    if (c0 + 3 < NC1) {
      const float* w0 = cw + (c0 + 0) * 81;
      const float* w1 = cw + (c0 + 1) * 81;
      const float* w2 = cw + (c0 + 2) * 81;
      const float* w3 = cw + (c0 + 3) * 81;
#pragma unroll
      for (int k = 0; k < 81; ++k) {
        float xv = xr[k];
        acc0 += xv * w0[k]; acc1 += xv * w1[k];
        acc2 += xv * w2[k]; acc3 += xv * w3[k];
      }
    } else {
      // tail group g=37: channels 148,149 valid; 150,151 are zero pad
      const float* w0 = cw + (c0 + 0) * 81;
      const float* w1 = cw + (c0 + 1) * 81;
#pragma unroll
      for (int k = 0; k < 81; ++k) {
        float xv = xr[k];
        acc0 += xv * w0[k]; acc1 += xv * w1[k];
      }
    }
    float4 o;
    o.x = fmaxf(acc0, 0.f); o.y = fmaxf(acc1, 0.f);
    o.z = fmaxf(acc2, 0.f); o.w = fmaxf(acc3, 0.f);
    *(float4*)(As + g * 4) = o;
  }
}

// ---------------- K2: per-sample exact kth-largest (radix select on float bits) + max ----------------
__global__ __launch_bounds__(256) void kth_kernel(const float* __restrict__ A,
                                                  float* __restrict__ Tb,
                                                  float* __restrict__ ginv) {
  __shared__ unsigned hist[2048];
  __shared__ unsigned seg[256];
  __shared__ unsigned suf[256];
  __shared__ unsigned s_prefix, s_krem, s_max;
  int b = blockIdx.x, tid = threadIdx.x;
  const float4* Ab = (const float4*)(A + (size_t)b * NTOT);
  if (tid == 0) { s_prefix = 0u; s_krem = KG; s_max = 0u; }
  unsigned mymax = 0u;
  __syncthreads();
  for (int pass = 0; pass < 3; ++pass) {
    for (int i = tid; i < 2048; i += 256) hist[i] = 0u;
    __syncthreads();
    int shift = (pass == 0) ? 21 : (pass == 1 ? 10 : 0);
    int bits = (pass == 2) ? 10 : 11;
    unsigned mask = (1u << bits) - 1u;
    unsigned pfx = s_prefix;
    int hishift = shift + bits;
    for (int i = tid; i < NTOT / 4; i += 256) {
      float4 f = Ab[i];
      unsigned u0 = __float_as_uint(f.x), u1 = __float_as_uint(f.y);
      unsigned u2 = __float_as_uint(f.z), u3 = __float_as_uint(f.w);
      if (pass == 0) {
        mymax = max(mymax, max(max(u0, u1), max(u2, u3)));
        atomicAdd(&hist[u0 >> 21], 1u); atomicAdd(&hist[u1 >> 21], 1u);
        atomicAdd(&hist[u2 >> 21], 1u); atomicAdd(&hist[u3 >> 21], 1u);
      } else {
        if ((u0 >> hishift) == pfx) atomicAdd(&hist[(u0 >> shift) & mask], 1u);
        if ((u1 >> hishift) == pfx) atomicAdd(&hist[(u1 >> shift) & mask], 1u);
        if ((u2 >> hishift) == pfx) atomicAdd(&hist[(u2 >> shift) & mask], 1u);
        if ((u3 >> hishift) == pfx) atomicAdd(&hist[(u3 >> shift) & mask], 1u);
      }
    }
    if (pass == 0) atomicMax(&s_max, mymax);
    __syncthreads();
    int segsz = (1 << bits) >> 8;
    unsigned ss = 0u;
    for (int j = 0; j < segsz; ++j) ss += hist[tid * segsz + j];
    seg[tid] = ss; suf[tid] = ss;
    __syncthreads();
    for (int st = 1; st < 256; st <<= 1) {
      unsigned add = (tid + st < 256) ? suf[tid + st] : 0u;
      __syncthreads();
      suf[tid] += add;
      __syncthreads();
    }
    unsigned k = s_krem;
    unsigned above = suf[tid] - seg[tid];
    if (above < k && suf[tid] >= k) {
      unsigned cum = above;
      int dsel = tid * segsz;
      for (int d2 = segsz - 1; d2 >= 0; --d2) {
        int dd = tid * segsz + d2;
        if (cum + hist[dd] >= k) { dsel = dd; break; }
        cum += hist[dd];
      }
      s_prefix = (pfx << bits) | (unsigned)dsel;
      s_krem = k - cum;
    }
    __syncthreads();
  }
  if (tid == 0) {
    Tb[b] = __uint_as_float(s_prefix);
    float gm = __uint_as_float(s_max);
    ginv[b] = (gm == 0.0f) ? 0.0f : 1.0f / gm;
  }
}

// ---------------- K3: per-location top-10 + embed + PE -> seq (in d_out) ----------------
__global__ __launch_bounds__(256) void seq_kernel(const float* __restrict__ A,
                                                  const float* __restrict__ Tb,
                                                  const float* __restrict__ ginv,
                                                  const float* __restrict__ CE,
                                                  const float* __restrict__ pos,
                                                  float* __restrict__ seq) {
  int wave = threadIdx.x >> 6, lane = threadIdx.x & 63;
  int loc = blockIdx.x * 4 + wave;
  int b = loc / HW, s = loc % HW;
  const float* base = A + (size_t)b * NTOT + s * CSTRIDE;
  float T = Tb[b];
  float v0 = base[lane];
  float v1 = base[64 + lane];
  float v2 = (lane < 22) ? base[128 + lane] : -1.0f;
  v0 = (v0 >= T) ? v0 : 0.0f;
  v1 = (v1 >= T) ? v1 : 0.0f;
  if (lane < 22) v2 = (v2 >= T) ? v2 : 0.0f;
  int c0 = lane, c1 = 64 + lane, c2 = 128 + lane;
  if (v0 < v1) { float t = v0; v0 = v1; v1 = t; int tc = c0; c0 = c1; c1 = tc; }
  if (v0 < v2) { float t = v0; v0 = v2; v2 = t; int tc = c0; c0 = c2; c2 = tc; }
  if (v1 < v2) { float t = v1; v1 = v2; v2 = t; int tc = c1; c1 = c2; c2 = tc; }
  float acc = 0.0f;
  for (int it = 0; it < KCH; ++it) {
    float m = v0;
#pragma unroll
    for (int off = 32; off >= 1; off >>= 1) m = fmaxf(m, __shfl_xor(m, off));
    if (m <= 0.0f) break;
    unsigned long long msk = __ballot(v0 == m);
    int first = __ffsll(msk) - 1;
    int cw = __shfl(c0, first);
    if (lane == first) { v0 = v1; c0 = c1; v1 = v2; c1 = c2; v2 = -1.0f; }
    if (lane < 32) acc += m * CE[cw * 32 + lane];
  }
  if (lane < 32) {
    float o = acc * ginv[b] + pos[s * 32 + lane];
    seq[(size_t)loc * 32 + lane] = o;
  }
}

// ---------------- K4: one-layer MHA, one block per (sample, head) ----------------
__global__ __launch_bounds__(256) void attn_kernel(const float* __restrict__ seq,
                                                   const float* __restrict__ Wqkv,
                                                   const float* __restrict__ bqkv,
                                                   float* __restrict__ ctxo) {
  __shared__ float sq[HW * HDIM], sk[HW * HDIM], sv[HW * HDIM];
  int blk = blockIdx.x;
  int b = blk >> 2, h = blk & 3;
  int tid = threadIdx.x;
  if (tid < HW) {
    int s = tid;
    const float* row = seq + ((size_t)b * HW + s) * DD;
    float xr[32];
#pragma unroll
    for (int e = 0; e < 8; ++e) {
      float4 f = ((const float4*)row)[e];
      xr[e * 4 + 0] = f.x; xr[e * 4 + 1] = f.y; xr[e * 4 + 2] = f.z; xr[e * 4 + 3] = f.w;
    }
#pragma unroll
    for (int which = 0; which < 3; ++which) {
      float* dst = (which == 0) ? sq : (which == 1) ? sk : sv;
#pragma unroll
      for (int d = 0; d < HDIM; ++d) {
        int grow = which * DD + h * HDIM + d;
        const float* wr = Wqkv + grow * DD;
        float acc = bqkv[grow];
#pragma unroll
        for (int e = 0; e < DD; ++e) acc += xr[e] * wr[e];
        dst[s * HDIM + d] = acc;
      }
    }
  }
  __syncthreads();
  if (tid >= HW) return;
  int qr = tid;
  float qreg[HDIM];
#pragma unroll
  for (int d = 0; d < HDIM; ++d) qreg[d] = sq[qr * HDIM + d];
  const float scale = 0.3535533905932738f;
  float mx = -1e30f;
  for (int t = 0; t < HW; ++t) {
    float sc = 0.f;
#pragma unroll
    for (int d = 0; d < HDIM; ++d) sc += qreg[d] * sk[t * HDIM + d];
    mx = fmaxf(mx, sc * scale);
  }
  float l = 0.f, ctx[HDIM];
#pragma unroll
  for (int d = 0; d < HDIM; ++d) ctx[d] = 0.f;
  for (int t = 0; t < HW; ++t) {
    float sc = 0.f;
#pragma unroll
    for (int d = 0; d < HDIM; ++d) sc += qreg[d] * sk[t * HDIM + d];
    float p = __expf(sc * scale - mx);
    l += p;
#pragma unroll
    for (int d = 0; d < HDIM; ++d) ctx[d] += p * sv[t * HDIM + d];
  }
  float inv = 1.0f / l;
  float* op = ctxo + ((size_t)b * HW + qr) * DD + h * HDIM;
  float4 o0, o1;
  o0.x = ctx[0] * inv; o0.y = ctx[1] * inv; o0.z = ctx[2] * inv; o0.w = ctx[3] * inv;
  o1.x = ctx[4] * inv; o1.y = ctx[5] * inv; o1.z = ctx[6] * inv; o1.w = ctx[7] * inv;
  ((float4*)op)[0] = o0; ((float4*)op)[1] = o1;
}

// ---------------- K5: out projection [N,32] x [32,32]^T + b ----------------
__global__ __launch_bounds__(256) void outproj_kernel(const float* __restrict__ ctx,
                                                      const float* __restrict__ Wo,
                                                      const float* __restrict__ bo,
                                                      float* __restrict__ out) {
  __shared__ float sw[32 * 32];
  __shared__ float sb2[32];
  int tid = threadIdx.x;
  for (int i = tid; i < 1024; i += 256) sw[i] = Wo[i];
  if (tid < 32) sb2[tid] = bo[tid];
  __syncthreads();
  int gid = blockIdx.x * 256 + tid;
  int row = gid >> 3, d4 = gid & 7;
  if (row >= NB * HW) return;
  const float* cr = ctx + (size_t)row * 32;
  float xr[32];
#pragma unroll
  for (int e = 0; e < 8; ++e) {
    float4 f = ((const float4*)cr)[e];
    xr[e * 4 + 0] = f.x; xr[e * 4 + 1] = f.y; xr[e * 4 + 2] = f.z; xr[e * 4 + 3] = f.w;
  }
  float4 o;
  float* oo = (float*)&o;
#pragma unroll
  for (int q = 0; q < 4; ++q) {
    int d = d4 * 4 + q;
    float acc = sb2[d];
#pragma unroll
    for (int e = 0; e < 32; ++e) acc += xr[e] * sw[d * 32 + e];
    oo[q] = acc;
  }
  *(float4*)(out + (size_t)row * 32 + d4 * 4) = o;
}

extern "C" void kernel_launch(void* const* d_in, const int* in_sizes, int n_in,
                              void* d_out, int out_size, void* d_ws, size_t ws_size,
                              hipStream_t stream) {
  const float* x  = (const float*)d_in[0];
  const float* cw = (const float*)d_in[1];
  const float* ce = (const float*)d_in[2];
  const float* wq = (const float*)d_in[3];
  const float* bq = (const float*)d_in[4];
  const float* wo = (const float*)d_in[5];
  const float* bo = (const float*)d_in[6];
  float* out = (float*)d_out;
  float* ws  = (float*)d_ws;

  float* A   = ws;
  float* Tb  = ws + (size_t)NB * NTOT;
  float* gi  = Tb + NB;
  float* pos = gi + NB;
  float* ctx = ws;   // alias A region (dead after seq_kernel)

  pos2d_kernel<<<(HW * DD + 255) / 256, 256, 0, stream>>>(pos);
  conv_kernel<<<NB, 256, 0, stream>>>(x, cw, A);
  kth_kernel<<<NB, 256, 0, stream>>>(A, Tb, gi);
  seq_kernel<<<(NB * HW) / 4, 256, 0, stream>>>(A, Tb, gi, ce, pos, out);   // seq -> d_out
  attn_kernel<<<NB * NHD, 256, 0, stream>>>(out, wq, bq, ctx);              // ctx -> ws
  outproj_kernel<<<(NB * HW * 8) / 256, 256, 0, stream>>>(ctx, wo, bo, out);
}

// Round 3
// 733.894 us; speedup vs baseline: 1.3499x; 1.3499x over previous
//
#include <hip/hip_runtime.h>
#include <math.h>

#define NC1 150
#define HW 196          // 14*14
#define CSTRIDE 152     // 150 padded to multiple of 4 (pad written as 0)
#define NTOT (HW*CSTRIDE)   // 29792
#define NB 1024
#define DD 32
#define NHD 4
#define HDIM 8
#define KG 2352         // ceil(0.08 * 150*14*14)
#define KCH 10

// ---------------- K0: 2D sinusoidal positional embedding [196,32] ----------------
__global__ void pos2d_kernel(float* __restrict__ pos) {
  int i = blockIdx.x * 256 + threadIdx.x;
  if (i >= HW * DD) return;
  int s = i >> 5, d = i & 31;
  int h = s / 14, w = s % 14;
  int p = (d < 16) ? h : w;
  int dd = (d < 16) ? d : d - 16;
  int j = dd >> 1;
  float dv = expf(-(logf(10000.0f) / 16.0f) * (float)(2 * j));
  float ang = (float)p * dv;
  pos[i] = (dd & 1) ? cosf(ang) : sinf(ang);
}

// ---------------- K1: conv 9x9 s2 p4 + relu, LDS-broadcast weights ----------------
// R3: weights staged in LDS (2 phases x 76 channels, rows padded to 84 floats so
// ds_read_b128 is 16B-aligned). All lanes read the SAME w quad -> LDS broadcast
// (conflict-free, fast) instead of the s_load -> lgkmcnt(0) scalar drain that
// made R1/R2 latency-bound. 16-channel chunks -> 4 consecutive float4 stores
// close each 64B output line quickly (less write amplification).
template<int NCH>
__device__ __forceinline__ void conv_chunk(const float* __restrict__ wp,
                                           const float* __restrict__ xr,
                                           float* __restrict__ dst) {
  float acc[NCH];
#pragma unroll
  for (int q = 0; q < NCH; ++q) acc[q] = 0.f;
#pragma unroll
  for (int pr = 0; pr < NCH / 2; ++pr) {           // 2 channels at a time
    const float* w0 = wp + (2 * pr + 0) * 84;
    const float* w1 = wp + (2 * pr + 1) * 84;
#pragma unroll
    for (int k = 0; k < 84; k += 4) {
      float4 a0 = *(const float4*)(w0 + k);
      float4 a1 = *(const float4*)(w1 + k);
      acc[2 * pr + 0] += xr[k + 0] * a0.x;
      acc[2 * pr + 0] += xr[k + 1] * a0.y;
      acc[2 * pr + 0] += xr[k + 2] * a0.z;
      acc[2 * pr + 0] += xr[k + 3] * a0.w;
      acc[2 * pr + 1] += xr[k + 0] * a1.x;
      acc[2 * pr + 1] += xr[k + 1] * a1.y;
      acc[2 * pr + 1] += xr[k + 2] * a1.z;
      acc[2 * pr + 1] += xr[k + 3] * a1.w;
    }
  }
#pragma unroll
  for (int q4 = 0; q4 < NCH / 4; ++q4) {
    float4 o;
    o.x = fmaxf(acc[q4 * 4 + 0], 0.f); o.y = fmaxf(acc[q4 * 4 + 1], 0.f);
    o.z = fmaxf(acc[q4 * 4 + 2], 0.f); o.w = fmaxf(acc[q4 * 4 + 3], 0.f);
    *(float4*)(dst + q4 * 4) = o;
  }
}

__global__ __launch_bounds__(256, 4) void conv_kernel(const float* __restrict__ x,
                                                      const float* __restrict__ cw,
                                                      float* __restrict__ A) {
  __shared__ float xs[784];
  __shared__ float wl[76 * 84];    // 25.5 KB
  int b = blockIdx.x, tid = threadIdx.x;
  if (tid < 196) ((float4*)xs)[tid] = ((const float4*)(x + (size_t)b * 784))[tid];
  __syncthreads();
  int s = (tid < 196) ? tid : 195;
  int h = s / 14, w = s % 14;
  float xr[84];
#pragma unroll
  for (int i = 0; i < 9; ++i) {
    int r = 2 * h - 4 + i;
    bool rok = (r >= 0 && r < 28);
#pragma unroll
    for (int j = 0; j < 9; ++j) {
      int cl = 2 * w - 4 + j;
      xr[i * 9 + j] = (rok && cl >= 0 && cl < 28) ? xs[r * 28 + cl] : 0.0f;
    }
  }
  xr[81] = 0.f; xr[82] = 0.f; xr[83] = 0.f;
  float* As = A + (size_t)b * NTOT + s * CSTRIDE;
  for (int ph = 0; ph < 2; ++ph) {
    int c0 = ph * 76;
    __syncthreads();                     // previous-phase readers done
    for (int i = tid; i < 76 * 84; i += 256) {
      int rr = i / 84, k = i - rr * 84;
      int c = c0 + rr;
      wl[i] = (k < 81 && c < NC1) ? cw[c * 81 + k] : 0.f;
    }
    __syncthreads();
    if (tid < 196) {
      conv_chunk<16>(wl + 0 * 84,  xr, As + c0 + 0);
      conv_chunk<16>(wl + 16 * 84, xr, As + c0 + 16);
      conv_chunk<16>(wl + 32 * 84, xr, As + c0 + 32);
      conv_chunk<16>(wl + 48 * 84, xr, As + c0 + 48);
      conv_chunk<12>(wl + 64 * 84, xr, As + c0 + 64);
    }
  }
}

// ---------------- K2: per-sample exact kth-largest (radix select on float bits) + max ----------------
__global__ __launch_bounds__(256) void kth_kernel(const float* __restrict__ A,
                                                  float* __restrict__ Tb,
                                                  float* __restrict__ ginv) {
  __shared__ unsigned hist[2048];
  __shared__ unsigned seg[256];
  __shared__ unsigned suf[256];
  __shared__ unsigned s_prefix, s_krem, s_max;
  int b = blockIdx.x, tid = threadIdx.x;
  const float4* Ab = (const float4*)(A + (size_t)b * NTOT);
  if (tid == 0) { s_prefix = 0u; s_krem = KG; s_max = 0u; }
  unsigned mymax = 0u;
  __syncthreads();
  for (int pass = 0; pass < 3; ++pass) {
    for (int i = tid; i < 2048; i += 256) hist[i] = 0u;
    __syncthreads();
    int shift = (pass == 0) ? 21 : (pass == 1 ? 10 : 0);
    int bits = (pass == 2) ? 10 : 11;
    unsigned mask = (1u << bits) - 1u;
    unsigned pfx = s_prefix;
    int hishift = shift + bits;
    for (int i = tid; i < NTOT / 4; i += 256) {
      float4 f = Ab[i];
      unsigned u0 = __float_as_uint(f.x), u1 = __float_as_uint(f.y);
      unsigned u2 = __float_as_uint(f.z), u3 = __float_as_uint(f.w);
      if (pass == 0) {
        mymax = max(mymax, max(max(u0, u1), max(u2, u3)));
        atomicAdd(&hist[u0 >> 21], 1u); atomicAdd(&hist[u1 >> 21], 1u);
        atomicAdd(&hist[u2 >> 21], 1u); atomicAdd(&hist[u3 >> 21], 1u);
      } else {
        if ((u0 >> hishift) == pfx) atomicAdd(&hist[(u0 >> shift) & mask], 1u);
        if ((u1 >> hishift) == pfx) atomicAdd(&hist[(u1 >> shift) & mask], 1u);
        if ((u2 >> hishift) == pfx) atomicAdd(&hist[(u2 >> shift) & mask], 1u);
        if ((u3 >> hishift) == pfx) atomicAdd(&hist[(u3 >> shift) & mask], 1u);
      }
    }
    if (pass == 0) atomicMax(&s_max, mymax);
    __syncthreads();
    int segsz = (1 << bits) >> 8;
    unsigned ss = 0u;
    for (int j = 0; j < segsz; ++j) ss += hist[tid * segsz + j];
    seg[tid] = ss; suf[tid] = ss;
    __syncthreads();
    for (int st = 1; st < 256; st <<= 1) {
      unsigned add = (tid + st < 256) ? suf[tid + st] : 0u;
      __syncthreads();
      suf[tid] += add;
      __syncthreads();
    }
    unsigned k = s_krem;
    unsigned above = suf[tid] - seg[tid];
    if (above < k && suf[tid] >= k) {
      unsigned cum = above;
      int dsel = tid * segsz;
      for (int d2 = segsz - 1; d2 >= 0; --d2) {
        int dd = tid * segsz + d2;
        if (cum + hist[dd] >= k) { dsel = dd; break; }
        cum += hist[dd];
      }
      s_prefix = (pfx << bits) | (unsigned)dsel;
      s_krem = k - cum;
    }
    __syncthreads();
  }
  if (tid == 0) {
    Tb[b] = __uint_as_float(s_prefix);
    float gm = __uint_as_float(s_max);
    ginv[b] = (gm == 0.0f) ? 0.0f : 1.0f / gm;
  }
}

// ---------------- K3: per-location top-10 + embed + PE -> seq (in d_out) ----------------
__global__ __launch_bounds__(256) void seq_kernel(const float* __restrict__ A,
                                                  const float* __restrict__ Tb,
                                                  const float* __restrict__ ginv,
                                                  const float* __restrict__ CE,
                                                  const float* __restrict__ pos,
                                                  float* __restrict__ seq) {
  int wave = threadIdx.x >> 6, lane = threadIdx.x & 63;
  int loc = blockIdx.x * 4 + wave;
  int b = loc / HW, s = loc % HW;
  const float* base = A + (size_t)b * NTOT + s * CSTRIDE;
  float T = Tb[b];
  float v0 = base[lane];
  float v1 = base[64 + lane];
  float v2 = (lane < 22) ? base[128 + lane] : -1.0f;
  v0 = (v0 >= T) ? v0 : 0.0f;
  v1 = (v1 >= T) ? v1 : 0.0f;
  if (lane < 22) v2 = (v2 >= T) ? v2 : 0.0f;
  int c0 = lane, c1 = 64 + lane, c2 = 128 + lane;
  if (v0 < v1) { float t = v0; v0 = v1; v1 = t; int tc = c0; c0 = c1; c1 = tc; }
  if (v0 < v2) { float t = v0; v0 = v2; v2 = t; int tc = c0; c0 = c2; c2 = tc; }
  if (v1 < v2) { float t = v1; v1 = v2; v2 = t; int tc = c1; c1 = c2; c2 = tc; }
  float acc = 0.0f;
  for (int it = 0; it < KCH; ++it) {
    float m = v0;
#pragma unroll
    for (int off = 32; off >= 1; off >>= 1) m = fmaxf(m, __shfl_xor(m, off));
    if (m <= 0.0f) break;
    unsigned long long msk = __ballot(v0 == m);
    int first = __ffsll(msk) - 1;
    int cw = __shfl(c0, first);
    if (lane == first) { v0 = v1; c0 = c1; v1 = v2; c1 = c2; v2 = -1.0f; }
    if (lane < 32) acc += m * CE[cw * 32 + lane];
  }
  if (lane < 32) {
    float o = acc * ginv[b] + pos[s * 32 + lane];
    seq[(size_t)loc * 32 + lane] = o;
  }
}

// ---------------- K4: one-layer MHA, one block per (sample, head) ----------------
__global__ __launch_bounds__(256) void attn_kernel(const float* __restrict__ seq,
                                                   const float* __restrict__ Wqkv,
                                                   const float* __restrict__ bqkv,
                                                   float* __restrict__ ctxo) {
  __shared__ float sq[HW * HDIM], sk[HW * HDIM], sv[HW * HDIM];
  int blk = blockIdx.x;
  int b = blk >> 2, h = blk & 3;
  int tid = threadIdx.x;
  if (tid < HW) {
    int s = tid;
    const float* row = seq + ((size_t)b * HW + s) * DD;
    float xr[32];
#pragma unroll
    for (int e = 0; e < 8; ++e) {
      float4 f = ((const float4*)row)[e];
      xr[e * 4 + 0] = f.x; xr[e * 4 + 1] = f.y; xr[e * 4 + 2] = f.z; xr[e * 4 + 3] = f.w;
    }
#pragma unroll
    for (int which = 0; which < 3; ++which) {
      float* dst = (which == 0) ? sq : (which == 1) ? sk : sv;
#pragma unroll
      for (int d = 0; d < HDIM; ++d) {
        int grow = which * DD + h * HDIM + d;
        const float* wr = Wqkv + grow * DD;
        float acc = bqkv[grow];
#pragma unroll
        for (int e = 0; e < DD; ++e) acc += xr[e] * wr[e];
        dst[s * HDIM + d] = acc;
      }
    }
  }
  __syncthreads();
  if (tid >= HW) return;
  int qr = tid;
  float qreg[HDIM];
#pragma unroll
  for (int d = 0; d < HDIM; ++d) qreg[d] = sq[qr * HDIM + d];
  const float scale = 0.3535533905932738f;
  float mx = -1e30f;
  for (int t = 0; t < HW; ++t) {
    float sc = 0.f;
#pragma unroll
    for (int d = 0; d < HDIM; ++d) sc += qreg[d] * sk[t * HDIM + d];
    mx = fmaxf(mx, sc * scale);
  }
  float l = 0.f, ctx[HDIM];
#pragma unroll
  for (int d = 0; d < HDIM; ++d) ctx[d] = 0.f;
  for (int t = 0; t < HW; ++t) {
    float sc = 0.f;
#pragma unroll
    for (int d = 0; d < HDIM; ++d) sc += qreg[d] * sk[t * HDIM + d];
    float p = __expf(sc * scale - mx);
    l += p;
#pragma unroll
    for (int d = 0; d < HDIM; ++d) ctx[d] += p * sv[t * HDIM + d];
  }
  float inv = 1.0f / l;
  float* op = ctxo + ((size_t)b * HW + qr) * DD + h * HDIM;
  float4 o0, o1;
  o0.x = ctx[0] * inv; o0.y = ctx[1] * inv; o0.z = ctx[2] * inv; o0.w = ctx[3] * inv;
  o1.x = ctx[4] * inv; o1.y = ctx[5] * inv; o1.z = ctx[6] * inv; o1.w = ctx[7] * inv;
  ((float4*)op)[0] = o0; ((float4*)op)[1] = o1;
}

// ---------------- K5: out projection [N,32] x [32,32]^T + b ----------------
__global__ __launch_bounds__(256) void outproj_kernel(const float* __restrict__ ctx,
                                                      const float* __restrict__ Wo,
                                                      const float* __restrict__ bo,
                                                      float* __restrict__ out) {
  __shared__ float sw[32 * 32];
  __shared__ float sb2[32];
  int tid = threadIdx.x;
  for (int i = tid; i < 1024; i += 256) sw[i] = Wo[i];
  if (tid < 32) sb2[tid] = bo[tid];
  __syncthreads();
  int gid = blockIdx.x * 256 + tid;
  int row = gid >> 3, d4 = gid & 7;
  if (row >= NB * HW) return;
  const float* cr = ctx + (size_t)row * 32;
  float xr[32];
#pragma unroll
  for (int e = 0; e < 8; ++e) {
    float4 f = ((const float4*)cr)[e];
    xr[e * 4 + 0] = f.x; xr[e * 4 + 1] = f.y; xr[e * 4 + 2] = f.z; xr[e * 4 + 3] = f.w;
  }
  float4 o;
  float* oo = (float*)&o;
#pragma unroll
  for (int q = 0; q < 4; ++q) {
    int d = d4 * 4 + q;
    float acc = sb2[d];
#pragma unroll
    for (int e = 0; e < 32; ++e) acc += xr[e] * sw[d * 32 + e];
    oo[q] = acc;
  }
  *(float4*)(out + (size_t)row * 32 + d4 * 4) = o;
}

extern "C" void kernel_launch(void* const* d_in, const int* in_sizes, int n_in,
                              void* d_out, int out_size, void* d_ws, size_t ws_size,
                              hipStream_t stream) {
  const float* x  = (const float*)d_in[0];
  const float* cw = (const float*)d_in[1];
  const float* ce = (const float*)d_in[2];
  const float* wq = (const float*)d_in[3];
  const float* bq = (const float*)d_in[4];
  const float* wo = (const float*)d_in[5];
  const float* bo = (const float*)d_in[6];
  float* out = (float*)d_out;
  float* ws  = (float*)d_ws;

  float* A   = ws;
  float* Tb  = ws + (size_t)NB * NTOT;
  float* gi  = Tb + NB;
  float* pos = gi + NB;
  float* ctx = ws;   // alias A region (dead after seq_kernel)

  pos2d_kernel<<<(HW * DD + 255) / 256, 256, 0, stream>>>(pos);
  conv_kernel<<<NB, 256, 0, stream>>>(x, cw, A);
  kth_kernel<<<NB, 256, 0, stream>>>(A, Tb, gi);
  seq_kernel<<<(NB * HW) / 4, 256, 0, stream>>>(A, Tb, gi, ce, pos, out);   // seq -> d_out
  attn_kernel<<<NB * NHD, 256, 0, stream>>>(out, wq, bq, ctx);              // ctx -> ws
  outproj_kernel<<<(NB * HW * 8) / 256, 256, 0, stream>>>(ctx, wo, bo, out);
}

// Round 4
// 673.431 us; speedup vs baseline: 1.4711x; 1.0898x over previous
//
#include <hip/hip_runtime.h>
#include <math.h>

#define NC1 150
#define HW 196          // 14*14
#define CSTRIDE 152     // 150 padded to multiple of 4 (pad written as 0)
#define NTOT (HW*CSTRIDE)   // 29792
#define NB 1024
#define DD 32
#define NHD 4
#define HDIM 8
#define KG 2352         // ceil(0.08 * 150*14*14)
#define KCH 10

// ---------------- K0: 2D sinusoidal positional embedding [196,32] ----------------
__global__ void pos2d_kernel(float* __restrict__ pos) {
  int i = blockIdx.x * 256 + threadIdx.x;
  if (i >= HW * DD) return;
  int s = i >> 5, d = i & 31;
  int h = s / 14, w = s % 14;
  int p = (d < 16) ? h : w;
  int dd = (d < 16) ? d : d - 16;
  int j = dd >> 1;
  float dv = expf(-(logf(10000.0f) / 16.0f) * (float)(2 * j));
  float ang = (float)p * dv;
  pos[i] = (dd & 1) ? cosf(ang) : sinf(ang);
}

// ---------------- K1: conv 9x9 s2 p4 + relu, LDS-broadcast weights ----------------
template<int NCH>
__device__ __forceinline__ void conv_chunk(const float* __restrict__ wp,
                                           const float* __restrict__ xr,
                                           float* __restrict__ dst) {
  float acc[NCH];
#pragma unroll
  for (int q = 0; q < NCH; ++q) acc[q] = 0.f;
#pragma unroll
  for (int pr = 0; pr < NCH / 2; ++pr) {
    const float* w0 = wp + (2 * pr + 0) * 84;
    const float* w1 = wp + (2 * pr + 1) * 84;
#pragma unroll
    for (int k = 0; k < 84; k += 4) {
      float4 a0 = *(const float4*)(w0 + k);
      float4 a1 = *(const float4*)(w1 + k);
      acc[2 * pr + 0] += xr[k + 0] * a0.x;
      acc[2 * pr + 0] += xr[k + 1] * a0.y;
      acc[2 * pr + 0] += xr[k + 2] * a0.z;
      acc[2 * pr + 0] += xr[k + 3] * a0.w;
      acc[2 * pr + 1] += xr[k + 0] * a1.x;
      acc[2 * pr + 1] += xr[k + 1] * a1.y;
      acc[2 * pr + 1] += xr[k + 2] * a1.z;
      acc[2 * pr + 1] += xr[k + 3] * a1.w;
    }
  }
#pragma unroll
  for (int q4 = 0; q4 < NCH / 4; ++q4) {
    float4 o;
    o.x = fmaxf(acc[q4 * 4 + 0], 0.f); o.y = fmaxf(acc[q4 * 4 + 1], 0.f);
    o.z = fmaxf(acc[q4 * 4 + 2], 0.f); o.w = fmaxf(acc[q4 * 4 + 3], 0.f);
    *(float4*)(dst + q4 * 4) = o;
  }
}

__global__ __launch_bounds__(256, 4) void conv_kernel(const float* __restrict__ x,
                                                      const float* __restrict__ cw,
                                                      float* __restrict__ A) {
  __shared__ float xs[784];
  __shared__ float wl[76 * 84];    // 25.5 KB
  int b = blockIdx.x, tid = threadIdx.x;
  if (tid < 196) ((float4*)xs)[tid] = ((const float4*)(x + (size_t)b * 784))[tid];
  __syncthreads();
  int s = (tid < 196) ? tid : 195;
  int h = s / 14, w = s % 14;
  float xr[84];
#pragma unroll
  for (int i = 0; i < 9; ++i) {
    int r = 2 * h - 4 + i;
    bool rok = (r >= 0 && r < 28);
#pragma unroll
    for (int j = 0; j < 9; ++j) {
      int cl = 2 * w - 4 + j;
      xr[i * 9 + j] = (rok && cl >= 0 && cl < 28) ? xs[r * 28 + cl] : 0.0f;
    }
  }
  xr[81] = 0.f; xr[82] = 0.f; xr[83] = 0.f;
  float* As = A + (size_t)b * NTOT + s * CSTRIDE;
  for (int ph = 0; ph < 2; ++ph) {
    int c0 = ph * 76;
    __syncthreads();
    for (int i = tid; i < 76 * 84; i += 256) {
      int rr = i / 84, k = i - rr * 84;
      int c = c0 + rr;
      wl[i] = (k < 81 && c < NC1) ? cw[c * 81 + k] : 0.f;
    }
    __syncthreads();
    if (tid < 196) {
      conv_chunk<16>(wl + 0 * 84,  xr, As + c0 + 0);
      conv_chunk<16>(wl + 16 * 84, xr, As + c0 + 16);
      conv_chunk<16>(wl + 32 * 84, xr, As + c0 + 32);
      conv_chunk<16>(wl + 48 * 84, xr, As + c0 + 48);
      conv_chunk<12>(wl + 64 * 84, xr, As + c0 + 64);
    }
  }
}

// ---------------- K2: per-sample exact kth-largest (radix select on float bits) + max ----------------
__global__ __launch_bounds__(256) void kth_kernel(const float* __restrict__ A,
                                                  float* __restrict__ Tb,
                                                  float* __restrict__ ginv) {
  __shared__ unsigned hist[2048];
  __shared__ unsigned seg[256];
  __shared__ unsigned suf[256];
  __shared__ unsigned s_prefix, s_krem, s_max;
  int b = blockIdx.x, tid = threadIdx.x;
  const float4* Ab = (const float4*)(A + (size_t)b * NTOT);
  if (tid == 0) { s_prefix = 0u; s_krem = KG; s_max = 0u; }
  unsigned mymax = 0u;
  __syncthreads();
  for (int pass = 0; pass < 3; ++pass) {
    for (int i = tid; i < 2048; i += 256) hist[i] = 0u;
    __syncthreads();
    int shift = (pass == 0) ? 21 : (pass == 1 ? 10 : 0);
    int bits = (pass == 2) ? 10 : 11;
    unsigned mask = (1u << bits) - 1u;
    unsigned pfx = s_prefix;
    int hishift = shift + bits;
    for (int i = tid; i < NTOT / 4; i += 256) {
      float4 f = Ab[i];
      unsigned u0 = __float_as_uint(f.x), u1 = __float_as_uint(f.y);
      unsigned u2 = __float_as_uint(f.z), u3 = __float_as_uint(f.w);
      if (pass == 0) {
        mymax = max(mymax, max(max(u0, u1), max(u2, u3)));
        atomicAdd(&hist[u0 >> 21], 1u); atomicAdd(&hist[u1 >> 21], 1u);
        atomicAdd(&hist[u2 >> 21], 1u); atomicAdd(&hist[u3 >> 21], 1u);
      } else {
        if ((u0 >> hishift) == pfx) atomicAdd(&hist[(u0 >> shift) & mask], 1u);
        if ((u1 >> hishift) == pfx) atomicAdd(&hist[(u1 >> shift) & mask], 1u);
        if ((u2 >> hishift) == pfx) atomicAdd(&hist[(u2 >> shift) & mask], 1u);
        if ((u3 >> hishift) == pfx) atomicAdd(&hist[(u3 >> shift) & mask], 1u);
      }
    }
    if (pass == 0) atomicMax(&s_max, mymax);
    __syncthreads();
    int segsz = (1 << bits) >> 8;
    unsigned ss = 0u;
    for (int j = 0; j < segsz; ++j) ss += hist[tid * segsz + j];
    seg[tid] = ss; suf[tid] = ss;
    __syncthreads();
    for (int st = 1; st < 256; st <<= 1) {
      unsigned add = (tid + st < 256) ? suf[tid + st] : 0u;
      __syncthreads();
      suf[tid] += add;
      __syncthreads();
    }
    unsigned k = s_krem;
    unsigned above = suf[tid] - seg[tid];
    if (above < k && suf[tid] >= k) {
      unsigned cum = above;
      int dsel = tid * segsz;
      for (int d2 = segsz - 1; d2 >= 0; --d2) {
        int dd = tid * segsz + d2;
        if (cum + hist[dd] >= k) { dsel = dd; break; }
        cum += hist[dd];
      }
      s_prefix = (pfx << bits) | (unsigned)dsel;
      s_krem = k - cum;
    }
    __syncthreads();
  }
  if (tid == 0) {
    Tb[b] = __uint_as_float(s_prefix);
    float gm = __uint_as_float(s_max);
    ginv[b] = (gm == 0.0f) ? 0.0f : 1.0f / gm;
  }
}

// ---------------- K3: per-location top-10 + embed + PE -> seq (in d_out) ----------------
__global__ __launch_bounds__(256) void seq_kernel(const float* __restrict__ A,
                                                  const float* __restrict__ Tb,
                                                  const float* __restrict__ ginv,
                                                  const float* __restrict__ CE,
                                                  const float* __restrict__ pos,
                                                  float* __restrict__ seq) {
  int wave = threadIdx.x >> 6, lane = threadIdx.x & 63;
  int loc = blockIdx.x * 4 + wave;
  int b = loc / HW, s = loc % HW;
  const float* base = A + (size_t)b * NTOT + s * CSTRIDE;
  float T = Tb[b];
  float v0 = base[lane];
  float v1 = base[64 + lane];
  float v2 = (lane < 22) ? base[128 + lane] : -1.0f;
  v0 = (v0 >= T) ? v0 : 0.0f;
  v1 = (v1 >= T) ? v1 : 0.0f;
  if (lane < 22) v2 = (v2 >= T) ? v2 : 0.0f;
  int c0 = lane, c1 = 64 + lane, c2 = 128 + lane;
  if (v0 < v1) { float t = v0; v0 = v1; v1 = t; int tc = c0; c0 = c1; c1 = tc; }
  if (v0 < v2) { float t = v0; v0 = v2; v2 = t; int tc = c0; c0 = c2; c2 = tc; }
  if (v1 < v2) { float t = v1; v1 = v2; v2 = t; int tc = c1; c1 = c2; c2 = tc; }
  float acc = 0.0f;
  for (int it = 0; it < KCH; ++it) {
    float m = v0;
#pragma unroll
    for (int off = 32; off >= 1; off >>= 1) m = fmaxf(m, __shfl_xor(m, off));
    if (m <= 0.0f) break;
    unsigned long long msk = __ballot(v0 == m);
    int first = __ffsll(msk) - 1;
    int cw = __shfl(c0, first);
    if (lane == first) { v0 = v1; c0 = c1; v1 = v2; c1 = c2; v2 = -1.0f; }
    if (lane < 32) acc += m * CE[cw * 32 + lane];
  }
  if (lane < 32) {
    float o = acc * ginv[b] + pos[s * 32 + lane];
    seq[(size_t)loc * 32 + lane] = o;
  }
}

// ---------------- K4: one-layer MHA, single-pass softmax w/ Cauchy-Schwarz shift ----------------
// R4: softmax shift M = |q|*max|k|*scale >= max score (shift-invariance is exact
// math; arg<=0 so no overflow; worst-case gap ~10 -> l >= 196*e^-10, safe in fp32).
// Deletes the entire max pre-pass (-8 FMA, -2 ds_read_b128 per (q,t)).
// Wqkv rows for this head staged in LDS (broadcast reads), not scalar s_loads.
__global__ __launch_bounds__(256) void attn_kernel(const float* __restrict__ seq,
                                                   const float* __restrict__ Wqkv,
                                                   const float* __restrict__ bqkv,
                                                   float* __restrict__ ctxo) {
  __shared__ float sq[HW * HDIM], sk[HW * HDIM], sv[HW * HDIM];
  __shared__ float swq[24 * DD];   // this head's 24 weight rows, 3 KB
  __shared__ float sbq[24];
  __shared__ unsigned s_kk;        // max |k|^2 over rows (bits of non-neg float)
  int blk = blockIdx.x;
  int b = blk >> 2, h = blk & 3;
  int tid = threadIdx.x;
  // stage weights: packed row r (0..23) = which (r>>3), d (r&7)
  for (int i = tid; i < 24 * DD; i += 256) {
    int r = i >> 5, e = i & 31;
    int grow = (r >> 3) * DD + h * HDIM + (r & 7);
    swq[i] = Wqkv[grow * DD + e];
  }
  if (tid < 24) sbq[tid] = bqkv[(tid >> 3) * DD + h * HDIM + (tid & 7)];
  if (tid == 0) s_kk = 0u;
  __syncthreads();
  if (tid < HW) {
    int s = tid;
    const float* row = seq + ((size_t)b * HW + s) * DD;
    float xr[32];
#pragma unroll
    for (int e = 0; e < 8; ++e) {
      float4 f = ((const float4*)row)[e];
      xr[e * 4 + 0] = f.x; xr[e * 4 + 1] = f.y; xr[e * 4 + 2] = f.z; xr[e * 4 + 3] = f.w;
    }
    float kk = 0.f;
#pragma unroll
    for (int r = 0; r < 24; ++r) {
      const float* wr = swq + r * DD;
      float acc = sbq[r];
#pragma unroll
      for (int e = 0; e < DD; e += 4) {
        float4 wv = *(const float4*)(wr + e);
        acc += xr[e + 0] * wv.x + xr[e + 1] * wv.y + xr[e + 2] * wv.z + xr[e + 3] * wv.w;
      }
      int which = r >> 3, d = r & 7;
      if (which == 0) sq[s * HDIM + d] = acc;
      else if (which == 1) { sk[s * HDIM + d] = acc; kk += acc * acc; }
      else sv[s * HDIM + d] = acc;
    }
    atomicMax(&s_kk, __float_as_uint(kk));
  }
  __syncthreads();
  if (tid >= HW) return;
  int qr = tid;
  float qreg[HDIM];
  float qq = 0.f;
#pragma unroll
  for (int d = 0; d < HDIM; ++d) { qreg[d] = sq[qr * HDIM + d]; qq += qreg[d] * qreg[d]; }
  const float scale = 0.3535533905932738f;        // 1/sqrt(8)
  float kkmax = __uint_as_float(s_kk);
  float negM = -sqrtf(qq * kkmax) * scale;        // -(|q| |k|max) * scale <= -max score
  float l = 0.f, ctx[HDIM];
#pragma unroll
  for (int d = 0; d < HDIM; ++d) ctx[d] = 0.f;
#pragma unroll 2
  for (int t = 0; t < HW; ++t) {
    const float* kr = sk + t * HDIM;
    float sc = 0.f;
#pragma unroll
    for (int d = 0; d < HDIM; ++d) sc += qreg[d] * kr[d];
    float p = __expf(fmaf(sc, scale, negM));      // arg <= 0, no overflow
    l += p;
    const float* vr = sv + t * HDIM;
#pragma unroll
    for (int d = 0; d < HDIM; ++d) ctx[d] += p * vr[d];
  }
  float inv = 1.0f / l;
  float* op = ctxo + ((size_t)b * HW + qr) * DD + h * HDIM;
  float4 o0, o1;
  o0.x = ctx[0] * inv; o0.y = ctx[1] * inv; o0.z = ctx[2] * inv; o0.w = ctx[3] * inv;
  o1.x = ctx[4] * inv; o1.y = ctx[5] * inv; o1.z = ctx[6] * inv; o1.w = ctx[7] * inv;
  ((float4*)op)[0] = o0; ((float4*)op)[1] = o1;
}

// ---------------- K5: out projection [N,32] x [32,32]^T + b ----------------
__global__ __launch_bounds__(256) void outproj_kernel(const float* __restrict__ ctx,
                                                      const float* __restrict__ Wo,
                                                      const float* __restrict__ bo,
                                                      float* __restrict__ out) {
  __shared__ float sw[32 * 32];
  __shared__ float sb2[32];
  int tid = threadIdx.x;
  for (int i = tid; i < 1024; i += 256) sw[i] = Wo[i];
  if (tid < 32) sb2[tid] = bo[tid];
  __syncthreads();
  int gid = blockIdx.x * 256 + tid;
  int row = gid >> 3, d4 = gid & 7;
  if (row >= NB * HW) return;
  const float* cr = ctx + (size_t)row * 32;
  float xr[32];
#pragma unroll
  for (int e = 0; e < 8; ++e) {
    float4 f = ((const float4*)cr)[e];
    xr[e * 4 + 0] = f.x; xr[e * 4 + 1] = f.y; xr[e * 4 + 2] = f.z; xr[e * 4 + 3] = f.w;
  }
  float4 o;
  float* oo = (float*)&o;
#pragma unroll
  for (int q = 0; q < 4; ++q) {
    int d = d4 * 4 + q;
    float acc = sb2[d];
#pragma unroll
    for (int e = 0; e < 32; ++e) acc += xr[e] * sw[d * 32 + e];
    oo[q] = acc;
  }
  *(float4*)(out + (size_t)row * 32 + d4 * 4) = o;
}

extern "C" void kernel_launch(void* const* d_in, const int* in_sizes, int n_in,
                              void* d_out, int out_size, void* d_ws, size_t ws_size,
                              hipStream_t stream) {
  const float* x  = (const float*)d_in[0];
  const float* cw = (const float*)d_in[1];
  const float* ce = (const float*)d_in[2];
  const float* wq = (const float*)d_in[3];
  const float* bq = (const float*)d_in[4];
  const float* wo = (const float*)d_in[5];
  const float* bo = (const float*)d_in[6];
  float* out = (float*)d_out;
  float* ws  = (float*)d_ws;

  float* A   = ws;
  float* Tb  = ws + (size_t)NB * NTOT;
  float* gi  = Tb + NB;
  float* pos = gi + NB;
  float* ctx = ws;   // alias A region (dead after seq_kernel)

  pos2d_kernel<<<(HW * DD + 255) / 256, 256, 0, stream>>>(pos);
  conv_kernel<<<NB, 256, 0, stream>>>(x, cw, A);
  kth_kernel<<<NB, 256, 0, stream>>>(A, Tb, gi);
  seq_kernel<<<(NB * HW) / 4, 256, 0, stream>>>(A, Tb, gi, ce, pos, out);   // seq -> d_out
  attn_kernel<<<NB * NHD, 256, 0, stream>>>(out, wq, bq, ctx);              // ctx -> ws
  outproj_kernel<<<(NB * HW * 8) / 256, 256, 0, stream>>>(ctx, wo, bo, out);
}